// Round 16
// baseline (387.669 us; speedup 1.0000x reference)
//
#include <hip/hip_runtime.h>
#include <hip/hip_bf16.h>
#include <stdint.h>

__device__ inline int imin(int a, int b) { return a < b ? a : b; }
__device__ inline int imax(int a, int b) { return a > b ? a : b; }
__device__ inline float bf2f(unsigned short u) {
    return __uint_as_float(((unsigned int)u) << 16);
}
__device__ inline unsigned short f2bf(float v) {
    unsigned int u = __float_as_uint(v);
    unsigned int r = u + 0x7FFFu + ((u >> 16) & 1u);
    return (unsigned short)(r >> 16);
}

typedef __attribute__((ext_vector_type(8))) short short8;   // 8 bf16 = 4 VGPRs
typedef __attribute__((ext_vector_type(4))) float floatx4;  // MFMA C/D

// ---------------- prologue: zero cnt + cast x->bf16 + weight casts ----------------

__global__ void k_prologue(int* __restrict__ cnt, int n,
                           const float* __restrict__ x, unsigned short* __restrict__ xb, size_t nx,
                           const float* __restrict__ W1, unsigned short* __restrict__ W1T,
                           const float* __restrict__ W2, unsigned short* __restrict__ W2T,
                           const float* __restrict__ W3, unsigned short* __restrict__ W3T) {
    size_t i = (size_t)blockIdx.x * 256 + threadIdx.x;
    if (i < (size_t)n) { cnt[i] = 0; }
    size_t j = i - n;
    if (i >= (size_t)n && j < nx) { xb[j] = f2bf(x[j]); }
    size_t k = j - nx;
    const int n1 = 128 * 256, n2 = 256 * 128, n3 = 128 * 64;
    if (j >= nx && k < (size_t)(n1 + n2 + n3)) {
        int idx = (int)k;
        if (idx < n1) {
            int kk = idx >> 8, nn = idx & 255;            // W1: K=128, Nc=256
            W1T[nn * 128 + kk] = f2bf(W1[idx]);
        } else if (idx < n1 + n2) {
            int jj = idx - n1;
            int kk = jj >> 7, nn = jj & 127;              // W2: K=256, Nc=128
            W2T[nn * 256 + kk] = f2bf(W2[jj]);
        } else {
            int jj = idx - n1 - n2;
            int kk = jj >> 6, nn = jj & 63;               // W3: K=128, Nc=64
            W3T[nn * 128 + kk] = f2bf(W3[jj]);
        }
    }
}

// ---------------- CSR build (padded-to-8 segments) ----------------

__global__ void k_count(const int* __restrict__ col, int* __restrict__ cnt, int E, int n) {
    int e = blockIdx.x * blockDim.x + threadIdx.x;
    if (e < E) {
        int c = imax(0, imin(col[e], n - 1));
        atomicAdd(&cnt[c], 1);
    }
}

__global__ __launch_bounds__(256) void k_scan1(const int* __restrict__ cnt,
                                               int* __restrict__ partial,
                                               int* __restrict__ bsum, int n) {
    __shared__ int tmp[256];
    int i = blockIdx.x * 256 + threadIdx.x;
    int v = (i < n) ? ((cnt[i] + 7) & ~7) : 0;
    tmp[threadIdx.x] = v;
    __syncthreads();
    #pragma unroll
    for (int s = 1; s < 256; s <<= 1) {
        int t = (threadIdx.x >= s) ? tmp[threadIdx.x - s] : 0;
        __syncthreads();
        tmp[threadIdx.x] += t;
        __syncthreads();
    }
    if (i < n) partial[i] = tmp[threadIdx.x] - v;
    if (threadIdx.x == 255) bsum[blockIdx.x] = tmp[255];
}

__global__ __launch_bounds__(256) void k_scan2(const int* __restrict__ bsum,
                                               int* __restrict__ bsumoff, int nb) {
    __shared__ int tmp[256];
    __shared__ int carry;
    if (threadIdx.x == 0) carry = 0;
    __syncthreads();
    for (int base = 0; base < nb; base += 256) {
        int i = base + threadIdx.x;
        int v = (i < nb) ? bsum[i] : 0;
        tmp[threadIdx.x] = v;
        __syncthreads();
        #pragma unroll
        for (int s = 1; s < 256; s <<= 1) {
            int t = (threadIdx.x >= s) ? tmp[threadIdx.x - s] : 0;
            __syncthreads();
            tmp[threadIdx.x] += t;
            __syncthreads();
        }
        if (i < nb) bsumoff[i] = carry + tmp[threadIdx.x] - v;
        __syncthreads();
        if (threadIdx.x == 0) carry += tmp[255];
        __syncthreads();
    }
}

// scan3 also writes the pad slots [offs+cnt, offs+pad8(cnt)) — deterministic,
// disjoint from k_fill's [offs, offs+cnt) range, so no ordering dependency.
template <bool USEW>
__global__ __launch_bounds__(256) void k_scan3(const int* __restrict__ partial,
                                               const int* __restrict__ bsumoff,
                                               const int* __restrict__ cnt,
                                               int* __restrict__ offs, int* __restrict__ cursor,
                                               float* __restrict__ dinv,
                                               unsigned long long* __restrict__ edges,
                                               int* __restrict__ csr_src,
                                               int n) {
    int i = blockIdx.x * 256 + threadIdx.x;
    if (i >= n) return;
    int v = partial[i] + bsumoff[blockIdx.x];
    int c = imax(cnt[i], 0);
    offs[i] = v;
    cursor[i] = v;
    if (i == n - 1) offs[n] = v + ((c + 7) & ~7);
    float d = (float)c + 1.0f;
    dinv[i] = rsqrtf(d);
    int end = v + ((c + 7) & ~7);
    for (int p = v + c; p < end; p++) {
        if (USEW) edges[p] = 0ull;
        else csr_src[p] = 0;
    }
}

// AoS {src, w} packed in 8B ULL, 1 edge/thread, non-temporal payload store.
template <bool USEW>
__global__ void k_fill(const int* __restrict__ row, const int* __restrict__ col,
                       int* __restrict__ cursor, const float* __restrict__ dinv,
                       unsigned long long* __restrict__ edges, int* __restrict__ csr_src,
                       int E, int n, int cap) {
    int e = blockIdx.x * blockDim.x + threadIdx.x;
    if (e >= E) return;
    int c = imax(0, imin(col[e], n - 1));
    int r = imax(0, imin(row[e], n - 1));
    float w = dinv[r];                       // independent load, issued before atomic
    int pos = atomicAdd(&cursor[c], 1);
    pos = imax(0, imin(pos, cap - 1));
    if (USEW) {
        unsigned long long rec = (unsigned long long)(unsigned)r
                               | ((unsigned long long)__float_as_uint(w) << 32);
        __builtin_nontemporal_store(rec, &edges[pos]);
    } else {
        __builtin_nontemporal_store(r, &csr_src[pos]);
    }
}

// ---------------- MFMA GEMM: H = act(bf16) @ W(bf16 WT), fp32 acc, bf16 out ----------------
// block: 128 rows x NT cols; wave w = rows w*32..w*32+31 (2 row-tiles of 16).
// LDS rows stride 40 shorts (80 B) -> 2-way bank aliasing only (free).
// Verified layouts: A[m=lane&15][k=quad*8+j]; B[k][n=lane&15]; C/D row=quad*4+reg, col=lane&15.

template <int NT, int FOUT, bool EPI>
__global__ __launch_bounds__(256) void k_gemm_mfma(const unsigned short* __restrict__ act,
                                                   const unsigned short* __restrict__ WT,
                                                   unsigned short* __restrict__ H,
                                                   const float* __restrict__ bias,
                                                   int nrows, int Fin) {
    constexpr int CT = NT / 16;
    __shared__ __align__(16) unsigned short sA[128 * 40];
    __shared__ __align__(16) unsigned short sB[NT * 40];
    const int tid = threadIdx.x;
    const int w = tid >> 6;
    const int lane = tid & 63;
    const int quad = lane >> 4;
    const int l15 = lane & 15;
    const int row0 = blockIdx.x * 128;
    const int col0 = blockIdx.y * NT;

    floatx4 acc[2][CT] = {};

    const int sr = tid >> 1;
    const int sp = (tid & 1) * 16;

    for (int k0 = 0; k0 < Fin; k0 += 32) {
        __syncthreads();
        {
            int grow = row0 + sr;
            uint4 v0 = make_uint4(0, 0, 0, 0), v1 = make_uint4(0, 0, 0, 0);
            if (grow < nrows) {
                const uint4* ap = (const uint4*)&act[(size_t)grow * Fin + k0 + sp];
                v0 = ap[0]; v1 = ap[1];
            }
            uint4* dst = (uint4*)&sA[sr * 40 + sp];
            dst[0] = v0; dst[1] = v1;
        }
        if (NT == 128 || tid < 128) {
            const uint4* wp = (const uint4*)&WT[(size_t)(col0 + sr) * Fin + k0 + sp];
            uint4* dst = (uint4*)&sB[sr * 40 + sp];
            dst[0] = wp[0]; dst[1] = wp[1];
        }
        __syncthreads();

        short8 bfr[CT];
        #pragma unroll
        for (int ct = 0; ct < CT; ct++)
            bfr[ct] = *(const short8*)&sB[(ct * 16 + l15) * 40 + quad * 8];
        #pragma unroll
        for (int rt = 0; rt < 2; rt++) {
            short8 afr = *(const short8*)&sA[(w * 32 + rt * 16 + l15) * 40 + quad * 8];
            #pragma unroll
            for (int ct = 0; ct < CT; ct++)
                acc[rt][ct] = __builtin_amdgcn_mfma_f32_16x16x32_bf16(afr, bfr[ct], acc[rt][ct], 0, 0, 0);
        }
    }

    #pragma unroll
    for (int rt = 0; rt < 2; rt++) {
        #pragma unroll
        for (int ct = 0; ct < CT; ct++) {
            int gcol = col0 + ct * 16 + l15;
            #pragma unroll
            for (int r = 0; r < 4; r++) {
                int grow = row0 + w * 32 + rt * 16 + quad * 4 + r;
                if (grow < nrows) {
                    float v = acc[rt][ct][r];
                    if (EPI) v = fmaxf(v + bias[gcol], 0.f);
                    H[(size_t)grow * FOUT + gcol] = f2bf(v);
                }
            }
        }
    }
}

// ---------------- small GEMMs (bf16 act in, bf16 out) ----------------

__global__ __launch_bounds__(256) void k_gemm32(const unsigned short* __restrict__ act,
                                                const float* __restrict__ W,
                                                unsigned short* __restrict__ H,
                                                int nrows) {
    __shared__ __align__(16) float sA[32 * 68];
    __shared__ __align__(16) float sW[16 * 32];
    const int tid = threadIdx.x;
    const int row0 = blockIdx.x * 32;
    const int Fin = 64, strA = 68;

    for (int i = tid; i < 32 * Fin; i += 256) {
        int r = i >> 6;
        int k = i & 63;
        float v = 0.f;
        if (row0 + r < nrows) v = bf2f(act[(size_t)row0 * Fin + i]);
        sA[r * strA + k] = v;
    }

    const int rl = tid >> 3;
    const int cg = tid & 7;
    float a0 = 0.f, a1 = 0.f, a2 = 0.f, a3 = 0.f;

    for (int k0 = 0; k0 < Fin; k0 += 16) {
        __syncthreads();
        const float* wsrc = W + (size_t)k0 * 32;
        for (int i = tid; i < 16 * 32; i += 256) sW[i] = wsrc[i];
        __syncthreads();
        #pragma unroll 4
        for (int kk = 0; kk < 16; kk++) {
            float a = sA[rl * strA + k0 + kk];
            float4 wv = *(const float4*)&sW[kk * 32 + cg * 4];
            a0 = fmaf(a, wv.x, a0);
            a1 = fmaf(a, wv.y, a1);
            a2 = fmaf(a, wv.z, a2);
            a3 = fmaf(a, wv.w, a3);
        }
    }

    const int rowi = row0 + rl;
    if (rowi < nrows) {
        unsigned short* hp = &H[(size_t)rowi * 32 + cg * 4];
        hp[0] = f2bf(a0); hp[1] = f2bf(a1); hp[2] = f2bf(a2); hp[3] = f2bf(a3);
    }
}

__global__ void k_gemm_heads(const unsigned short* __restrict__ act,
                             const float* __restrict__ Wmu, const float* __restrict__ Wls,
                             unsigned short* __restrict__ H, int nrows) {
    int idx = blockIdx.x * blockDim.x + threadIdx.x;
    if (idx >= nrows * 32) return;
    int r = idx >> 5;
    int c = idx & 31;
    const float* Wp = (c < 16) ? Wmu : Wls;
    int cc = c & 15;
    float acc = 0.f;
    #pragma unroll 8
    for (int k = 0; k < 32; k++)
        acc = fmaf(bf2f(act[(size_t)r * 32 + k]), Wp[k * 16 + cc], acc);
    H[idx] = f2bf(acc);
}

// ---- aggregation over bf16 H, 8x-unrolled padded CSR; bf16 out ----

template <int F, bool RELU, bool HASBIAS, bool USEW>
__global__ __launch_bounds__(256) void k_aggb(const unsigned short* __restrict__ Hb,
                                              unsigned short* __restrict__ out,
                                              const int* __restrict__ offs,
                                              const unsigned long long* __restrict__ edges,
                                              const int* __restrict__ src,
                                              const float* __restrict__ dinv,
                                              const float* __restrict__ bias,
                                              int nnodes, int Ecap) {
    constexpr int TPN = (F >= 128) ? 64 : F / 2;
    int t = blockIdx.x * 256 + threadIdx.x;
    int node = t / TPN;
    int ln = t % TPN;
    if (node >= nnodes) return;
    int f0 = 2 * ln;

    float di = dinv[node];
    ushort2 sv = *(const ushort2*)&Hb[(size_t)node * F + f0];
    float acc0 = di * bf2f(sv.x);
    float acc1 = di * bf2f(sv.y);

    int s0 = offs[node];
    int s1 = offs[node + 1];
    s0 = imax(0, imin(s0, Ecap));
    s1 = imax(s0, imin(s1, Ecap));
    for (int e = s0; e < s1; e += 8) {
        int sr[8];
        float wv[8];
        if (USEW) {
            #pragma unroll
            for (int q = 0; q < 4; q++) {
                uint4 pr = *(const uint4*)(edges + e + 2 * q);
                sr[2 * q] = (int)pr.x;     wv[2 * q] = __uint_as_float(pr.y);
                sr[2 * q + 1] = (int)pr.z; wv[2 * q + 1] = __uint_as_float(pr.w);
            }
        } else {
            int4 a = *(const int4*)(src + e);
            int4 b = *(const int4*)(src + e + 4);
            sr[0] = a.x; sr[1] = a.y; sr[2] = a.z; sr[3] = a.w;
            sr[4] = b.x; sr[5] = b.y; sr[6] = b.z; sr[7] = b.w;
            #pragma unroll
            for (int q = 0; q < 8; q++) wv[q] = dinv[sr[q]];
        }
        ushort2 h[8];
        #pragma unroll
        for (int q = 0; q < 8; q++)
            h[q] = *(const ushort2*)&Hb[(size_t)sr[q] * F + f0];
        #pragma unroll
        for (int q = 0; q < 8; q++) {
            acc0 = fmaf(wv[q], bf2f(h[q].x), acc0);
            acc1 = fmaf(wv[q], bf2f(h[q].y), acc1);
        }
    }
    float v0 = di * acc0;
    float v1 = di * acc1;
    if (HASBIAS) { v0 += bias[f0]; v1 += bias[f0 + 1]; }
    if (RELU) { v0 = fmaxf(v0, 0.f); v1 = fmaxf(v1, 0.f); }
    ushort2 o; o.x = f2bf(v0); o.y = f2bf(v1);
    *(ushort2*)&out[(size_t)node * F + f0] = o;
}

// fused heads aggregation: F=32 (mu 0..15, logstd 16..31), fp32 split output to d_out
template <bool USEW>
__global__ __launch_bounds__(256) void k_agg_heads(const unsigned short* __restrict__ Hb,
                                                   float* __restrict__ out,
                                                   const int* __restrict__ offs,
                                                   const unsigned long long* __restrict__ edges,
                                                   const int* __restrict__ src,
                                                   const float* __restrict__ dinv,
                                                   const float* __restrict__ bmu, const float* __restrict__ bls,
                                                   int nnodes, int Ecap) {
    constexpr int F = 32, TPN = 16;
    int t = blockIdx.x * 256 + threadIdx.x;
    int node = t / TPN;
    int ln = t % TPN;
    if (node >= nnodes) return;
    int f0 = 2 * ln;

    float di = dinv[node];
    ushort2 sv = *(const ushort2*)&Hb[(size_t)node * F + f0];
    float acc0 = di * bf2f(sv.x);
    float acc1 = di * bf2f(sv.y);

    int s0 = offs[node];
    int s1 = offs[node + 1];
    s0 = imax(0, imin(s0, Ecap));
    s1 = imax(s0, imin(s1, Ecap));
    for (int e = s0; e < s1; e += 8) {
        int sr[8];
        float wv[8];
        if (USEW) {
            #pragma unroll
            for (int q = 0; q < 4; q++) {
                uint4 pr = *(const uint4*)(edges + e + 2 * q);
                sr[2 * q] = (int)pr.x;     wv[2 * q] = __uint_as_float(pr.y);
                sr[2 * q + 1] = (int)pr.z; wv[2 * q + 1] = __uint_as_float(pr.w);
            }
        } else {
            int4 a = *(const int4*)(src + e);
            int4 b = *(const int4*)(src + e + 4);
            sr[0] = a.x; sr[1] = a.y; sr[2] = a.z; sr[3] = a.w;
            sr[4] = b.x; sr[5] = b.y; sr[6] = b.z; sr[7] = b.w;
            #pragma unroll
            for (int q = 0; q < 8; q++) wv[q] = dinv[sr[q]];
        }
        ushort2 h[8];
        #pragma unroll
        for (int q = 0; q < 8; q++)
            h[q] = *(const ushort2*)&Hb[(size_t)sr[q] * F + f0];
        #pragma unroll
        for (int q = 0; q < 8; q++) {
            acc0 = fmaf(wv[q], bf2f(h[q].x), acc0);
            acc1 = fmaf(wv[q], bf2f(h[q].y), acc1);
        }
    }
    const float* bp = (f0 < 16) ? bmu : bls;
    int fb = f0 & 15;
    float v0 = fmaf(di, acc0, bp[fb]);
    float v1 = fmaf(di, acc1, bp[fb + 1]);
    float* op = (f0 < 16) ? (out + (size_t)node * 16 + fb)
                          : (out + (size_t)nnodes * 16 + (size_t)node * 16 + fb);
    *(float2*)op = make_float2(v0, v1);
}

// ---------------- pipeline ----------------

template <bool USEW>
static void run_pipeline(void* const* d_in, void* d_out, void* d_ws,
                         int N, int E, hipStream_t stream) {
    const float* x  = (const float*)d_in[0];
    const int* ei   = (const int*)d_in[1];
    const float* W1 = (const float*)d_in[2];
    const float* b1 = (const float*)d_in[3];
    const float* W2 = (const float*)d_in[4];
    const float* b2 = (const float*)d_in[5];
    const float* W3 = (const float*)d_in[6];
    const float* b3 = (const float*)d_in[7];
    const float* W4 = (const float*)d_in[8];
    const float* b4 = (const float*)d_in[9];
    const float* Wmu = (const float*)d_in[10];
    const float* bmu = (const float*)d_in[11];
    const float* Wls = (const float*)d_in[12];
    const float* bls = (const float*)d_in[13];
    const int* row = ei;        // edge_index[0] = source
    const int* col = ei + E;    // edge_index[1] = target
    const int nb = (N + 255) / 256;
    const int E8 = E + 8 * N;   // capacity with pad-to-8

    auto align16 = [](char* p) {
        return (char*)(((uintptr_t)p + 15) & ~(uintptr_t)15);
    };
    char* p = (char*)d_ws;
    unsigned short* act = (unsigned short*)p;    p += (size_t)N * 256 * 2;
    unsigned short* H = (unsigned short*)p;      p += (size_t)N * 256 * 2;
    unsigned short* xb = H;                      // alias (dead before H first write)
    unsigned short* xa = (unsigned short*)p;     p += (size_t)N * 128 * 2;
    float* dinv = (float*)p;                     p += (size_t)N * 4;
    int* cnt = (int*)p;                          p += (size_t)N * 4;
    int* offs = (int*)p;                         p += (size_t)(N + 1) * 4;
    int* cursor = (int*)p;                       p += (size_t)N * 4;
    int* partial = (int*)p;                      p += (size_t)N * 4;
    int* bsum = (int*)p;                         p += (size_t)nb * 4;
    int* bsumoff = (int*)p;                      p += (size_t)nb * 4;
    p = align16(p);
    unsigned short* W1T = (unsigned short*)p;    p += 256 * 128 * 2;
    unsigned short* W2T = (unsigned short*)p;    p += 128 * 256 * 2;
    unsigned short* W3T = (unsigned short*)p;    p += 64 * 128 * 2;
    p = align16(p);
    unsigned long long* edges = nullptr;
    int* csr_src = nullptr;
    if (USEW) edges = (unsigned long long*)p;
    else      csr_src = (int*)p;

    // prologue: zero cnt, x->bf16, weight casts (one kernel)
    {
        size_t total = (size_t)N + (size_t)N * 128 + (128 * 256 + 256 * 128 + 128 * 64);
        k_prologue<<<(unsigned)((total + 255) / 256), 256, 0, stream>>>(
            cnt, N, x, xb, (size_t)N * 128, W1, W1T, W2, W2T, W3, W3T);
    }
    // CSR + norms (pad fused into scan3)
    k_count<<<(E + 255) / 256, 256, 0, stream>>>(col, cnt, E, N);
    k_scan1<<<nb, 256, 0, stream>>>(cnt, partial, bsum, N);
    k_scan2<<<1, 256, 0, stream>>>(bsum, bsumoff, nb);
    k_scan3<USEW><<<nb, 256, 0, stream>>>(partial, bsumoff, cnt, offs, cursor, dinv, edges, csr_src, N);
    k_fill<USEW><<<(E + 255) / 256, 256, 0, stream>>>(row, col, cursor, dinv, edges, csr_src, E, N, E8);

    const int gx = (N + 127) / 128;
    // layer 1: act1 = relu( (Â x) W1 + b1 )
    k_aggb<128, false, false, USEW><<<(unsigned)(((size_t)N * 64 + 255) / 256), 256, 0, stream>>>(xb, xa, offs, edges, csr_src, dinv, nullptr, N, E8);
    k_gemm_mfma<128, 256, true><<<dim3(gx, 2), 256, 0, stream>>>(xa, W1T, act, b1, N, 128);
    // layer 2
    k_gemm_mfma<128, 128, false><<<dim3(gx, 1), 256, 0, stream>>>(act, W2T, H, nullptr, N, 256);
    k_aggb<128, true, true, USEW><<<(unsigned)(((size_t)N * 64 + 255) / 256), 256, 0, stream>>>(H, act, offs, edges, csr_src, dinv, b2, N, E8);
    // layer 3
    k_gemm_mfma<64, 64, false><<<dim3(gx, 1), 256, 0, stream>>>(act, W3T, H, nullptr, N, 128);
    k_aggb<64, true, true, USEW><<<(unsigned)(((size_t)N * 32 + 255) / 256), 256, 0, stream>>>(H, act, offs, edges, csr_src, dinv, b3, N, E8);
    // layer 4
    k_gemm32<<<(N + 31) / 32, 256, 0, stream>>>(act, W4, H, N);
    k_aggb<32, true, true, USEW><<<(unsigned)(((size_t)N * 16 + 255) / 256), 256, 0, stream>>>(H, act, offs, edges, csr_src, dinv, b4, N, E8);
    // fused heads
    float* outF = (float*)d_out;
    k_gemm_heads<<<(unsigned)(((size_t)N * 32 + 255) / 256), 256, 0, stream>>>(act, Wmu, Wls, H, N);
    k_agg_heads<USEW><<<(unsigned)(((size_t)N * 16 + 255) / 256), 256, 0, stream>>>(H, outF, offs, edges, csr_src, dinv, bmu, bls, N, E8);
}

extern "C" void kernel_launch(void* const* d_in, const int* in_sizes, int n_in,
                              void* d_out, int out_size, void* d_ws, size_t ws_size,
                              hipStream_t stream) {
    const int N = in_sizes[0] / 128;
    const int E = in_sizes[1] / 2;
    const int nb = (N + 255) / 256;
    const size_t E8 = (size_t)E + 8 * (size_t)N;

    size_t fixed = (size_t)N * 256 * 2 * 2 + (size_t)N * 128 * 2
                 + (size_t)N * 4 * 5 + 4 + (size_t)nb * 8
                 + (256 * 128 + 128 * 256 + 64 * 128) * 2 + 96;
    size_t need_w = fixed + E8 * 8;
    if (ws_size >= need_w)
        run_pipeline<true>(d_in, d_out, d_ws, N, E, stream);
    else
        run_pipeline<false>(d_in, d_out, d_ws, N, E, stream);
}

// Round 17
// 341.494 us; speedup vs baseline: 1.1352x; 1.1352x over previous
//
#include <hip/hip_runtime.h>
#include <hip/hip_bf16.h>
#include <stdint.h>

__device__ inline int imin(int a, int b) { return a < b ? a : b; }
__device__ inline int imax(int a, int b) { return a > b ? a : b; }
__device__ inline float bf2f(unsigned short u) {
    return __uint_as_float(((unsigned int)u) << 16);
}
__device__ inline unsigned short f2bf(float v) {
    unsigned int u = __float_as_uint(v);
    unsigned int r = u + 0x7FFFu + ((u >> 16) & 1u);
    return (unsigned short)(r >> 16);
}

typedef __attribute__((ext_vector_type(8))) short short8;   // 8 bf16 = 4 VGPRs
typedef __attribute__((ext_vector_type(4))) float floatx4;  // MFMA C/D

// ---------------- prologue: zero cnt + cast x->bf16 + weight casts ----------------

__global__ void k_prologue(int* __restrict__ cnt, int n,
                           const float* __restrict__ x, unsigned short* __restrict__ xb, size_t nx,
                           const float* __restrict__ W1, unsigned short* __restrict__ W1T,
                           const float* __restrict__ W2, unsigned short* __restrict__ W2T,
                           const float* __restrict__ W3, unsigned short* __restrict__ W3T) {
    size_t i = (size_t)blockIdx.x * 256 + threadIdx.x;
    if (i < (size_t)n) { cnt[i] = 0; }
    size_t j = i - n;
    if (i >= (size_t)n && j < nx) { xb[j] = f2bf(x[j]); }
    size_t k = j - nx;
    const int n1 = 128 * 256, n2 = 256 * 128, n3 = 128 * 64;
    if (j >= nx && k < (size_t)(n1 + n2 + n3)) {
        int idx = (int)k;
        if (idx < n1) {
            int kk = idx >> 8, nn = idx & 255;            // W1: K=128, Nc=256
            W1T[nn * 128 + kk] = f2bf(W1[idx]);
        } else if (idx < n1 + n2) {
            int jj = idx - n1;
            int kk = jj >> 7, nn = jj & 127;              // W2: K=256, Nc=128
            W2T[nn * 256 + kk] = f2bf(W2[jj]);
        } else {
            int jj = idx - n1 - n2;
            int kk = jj >> 6, nn = jj & 63;               // W3: K=128, Nc=64
            W3T[nn * 128 + kk] = f2bf(W3[jj]);
        }
    }
}

// ---------------- CSR build (padded-to-8 segments, atomic-free fill) ----------------

// count + capture per-edge rank (arrival order within its target's segment)
__global__ void k_count(const int* __restrict__ col, int* __restrict__ cnt,
                        int* __restrict__ rank, int E, int n) {
    int e = blockIdx.x * blockDim.x + threadIdx.x;
    if (e < E) {
        int c = imax(0, imin(col[e], n - 1));
        rank[e] = atomicAdd(&cnt[c], 1);
    }
}

__global__ __launch_bounds__(256) void k_scan1(const int* __restrict__ cnt,
                                               int* __restrict__ partial,
                                               int* __restrict__ bsum, int n) {
    __shared__ int tmp[256];
    int i = blockIdx.x * 256 + threadIdx.x;
    int v = (i < n) ? ((cnt[i] + 7) & ~7) : 0;
    tmp[threadIdx.x] = v;
    __syncthreads();
    #pragma unroll
    for (int s = 1; s < 256; s <<= 1) {
        int t = (threadIdx.x >= s) ? tmp[threadIdx.x - s] : 0;
        __syncthreads();
        tmp[threadIdx.x] += t;
        __syncthreads();
    }
    if (i < n) partial[i] = tmp[threadIdx.x] - v;
    if (threadIdx.x == 255) bsum[blockIdx.x] = tmp[255];
}

__global__ __launch_bounds__(256) void k_scan2(const int* __restrict__ bsum,
                                               int* __restrict__ bsumoff, int nb) {
    __shared__ int tmp[256];
    __shared__ int carry;
    if (threadIdx.x == 0) carry = 0;
    __syncthreads();
    for (int base = 0; base < nb; base += 256) {
        int i = base + threadIdx.x;
        int v = (i < nb) ? bsum[i] : 0;
        tmp[threadIdx.x] = v;
        __syncthreads();
        #pragma unroll
        for (int s = 1; s < 256; s <<= 1) {
            int t = (threadIdx.x >= s) ? tmp[threadIdx.x - s] : 0;
            __syncthreads();
            tmp[threadIdx.x] += t;
            __syncthreads();
        }
        if (i < nb) bsumoff[i] = carry + tmp[threadIdx.x] - v;
        __syncthreads();
        if (threadIdx.x == 0) carry += tmp[255];
        __syncthreads();
    }
}

// scan3 writes offs and the pad slots [offs+cnt, offs+pad8(cnt)) — deterministic,
// disjoint from k_fill's [offs, offs+cnt) range, so no ordering dependency.
template <bool USEW>
__global__ __launch_bounds__(256) void k_scan3(const int* __restrict__ partial,
                                               const int* __restrict__ bsumoff,
                                               const int* __restrict__ cnt,
                                               int* __restrict__ offs,
                                               float* __restrict__ dinv,
                                               unsigned long long* __restrict__ edges,
                                               int* __restrict__ csr_src,
                                               int n) {
    int i = blockIdx.x * 256 + threadIdx.x;
    if (i >= n) return;
    int v = partial[i] + bsumoff[blockIdx.x];
    int c = imax(cnt[i], 0);
    offs[i] = v;
    if (i == n - 1) offs[n] = v + ((c + 7) & ~7);
    float d = (float)c + 1.0f;
    dinv[i] = rsqrtf(d);
    int end = v + ((c + 7) & ~7);
    for (int p = v + c; p < end; p++) {
        if (USEW) edges[p] = 0ull;
        else csr_src[p] = 0;
    }
}

// atomic-free: pos = offs[col] + rank[e]; pure loads + one independent store.
template <bool USEW>
__global__ void k_fill(const int* __restrict__ row, const int* __restrict__ col,
                       const int* __restrict__ offs, const int* __restrict__ rank,
                       const float* __restrict__ dinv,
                       unsigned long long* __restrict__ edges, int* __restrict__ csr_src,
                       int E, int n, int cap) {
    int e = blockIdx.x * blockDim.x + threadIdx.x;
    if (e >= E) return;
    int c = imax(0, imin(col[e], n - 1));
    int r = imax(0, imin(row[e], n - 1));
    int pos = offs[c] + rank[e];
    pos = imax(0, imin(pos, cap - 1));
    if (USEW) {
        unsigned long long rec = (unsigned long long)(unsigned)r
                               | ((unsigned long long)__float_as_uint(dinv[r]) << 32);
        edges[pos] = rec;
    } else {
        csr_src[pos] = r;
    }
}

// ---------------- MFMA GEMM: H = act(bf16) @ W(bf16 WT), fp32 acc, bf16 out ----------------
// block: 128 rows x NT cols; wave w = rows w*32..w*32+31 (2 row-tiles of 16).
// LDS rows stride 40 shorts (80 B) -> 2-way bank aliasing only (free).
// Verified layouts: A[m=lane&15][k=quad*8+j]; B[k][n=lane&15]; C/D row=quad*4+reg, col=lane&15.

template <int NT, int FOUT, bool EPI>
__global__ __launch_bounds__(256) void k_gemm_mfma(const unsigned short* __restrict__ act,
                                                   const unsigned short* __restrict__ WT,
                                                   unsigned short* __restrict__ H,
                                                   const float* __restrict__ bias,
                                                   int nrows, int Fin) {
    constexpr int CT = NT / 16;
    __shared__ __align__(16) unsigned short sA[128 * 40];
    __shared__ __align__(16) unsigned short sB[NT * 40];
    const int tid = threadIdx.x;
    const int w = tid >> 6;
    const int lane = tid & 63;
    const int quad = lane >> 4;
    const int l15 = lane & 15;
    const int row0 = blockIdx.x * 128;
    const int col0 = blockIdx.y * NT;

    floatx4 acc[2][CT] = {};

    const int sr = tid >> 1;
    const int sp = (tid & 1) * 16;

    for (int k0 = 0; k0 < Fin; k0 += 32) {
        __syncthreads();
        {
            int grow = row0 + sr;
            uint4 v0 = make_uint4(0, 0, 0, 0), v1 = make_uint4(0, 0, 0, 0);
            if (grow < nrows) {
                const uint4* ap = (const uint4*)&act[(size_t)grow * Fin + k0 + sp];
                v0 = ap[0]; v1 = ap[1];
            }
            uint4* dst = (uint4*)&sA[sr * 40 + sp];
            dst[0] = v0; dst[1] = v1;
        }
        if (NT == 128 || tid < 128) {
            const uint4* wp = (const uint4*)&WT[(size_t)(col0 + sr) * Fin + k0 + sp];
            uint4* dst = (uint4*)&sB[sr * 40 + sp];
            dst[0] = wp[0]; dst[1] = wp[1];
        }
        __syncthreads();

        short8 bfr[CT];
        #pragma unroll
        for (int ct = 0; ct < CT; ct++)
            bfr[ct] = *(const short8*)&sB[(ct * 16 + l15) * 40 + quad * 8];
        #pragma unroll
        for (int rt = 0; rt < 2; rt++) {
            short8 afr = *(const short8*)&sA[(w * 32 + rt * 16 + l15) * 40 + quad * 8];
            #pragma unroll
            for (int ct = 0; ct < CT; ct++)
                acc[rt][ct] = __builtin_amdgcn_mfma_f32_16x16x32_bf16(afr, bfr[ct], acc[rt][ct], 0, 0, 0);
        }
    }

    #pragma unroll
    for (int rt = 0; rt < 2; rt++) {
        #pragma unroll
        for (int ct = 0; ct < CT; ct++) {
            int gcol = col0 + ct * 16 + l15;
            #pragma unroll
            for (int r = 0; r < 4; r++) {
                int grow = row0 + w * 32 + rt * 16 + quad * 4 + r;
                if (grow < nrows) {
                    float v = acc[rt][ct][r];
                    if (EPI) v = fmaxf(v + bias[gcol], 0.f);
                    H[(size_t)grow * FOUT + gcol] = f2bf(v);
                }
            }
        }
    }
}

// ---------------- small GEMMs (bf16 act in, bf16 out) ----------------

__global__ __launch_bounds__(256) void k_gemm32(const unsigned short* __restrict__ act,
                                                const float* __restrict__ W,
                                                unsigned short* __restrict__ H,
                                                int nrows) {
    __shared__ __align__(16) float sA[32 * 68];
    __shared__ __align__(16) float sW[16 * 32];
    const int tid = threadIdx.x;
    const int row0 = blockIdx.x * 32;
    const int Fin = 64, strA = 68;

    for (int i = tid; i < 32 * Fin; i += 256) {
        int r = i >> 6;
        int k = i & 63;
        float v = 0.f;
        if (row0 + r < nrows) v = bf2f(act[(size_t)row0 * Fin + i]);
        sA[r * strA + k] = v;
    }

    const int rl = tid >> 3;
    const int cg = tid & 7;
    float a0 = 0.f, a1 = 0.f, a2 = 0.f, a3 = 0.f;

    for (int k0 = 0; k0 < Fin; k0 += 16) {
        __syncthreads();
        const float* wsrc = W + (size_t)k0 * 32;
        for (int i = tid; i < 16 * 32; i += 256) sW[i] = wsrc[i];
        __syncthreads();
        #pragma unroll 4
        for (int kk = 0; kk < 16; kk++) {
            float a = sA[rl * strA + k0 + kk];
            float4 wv = *(const float4*)&sW[kk * 32 + cg * 4];
            a0 = fmaf(a, wv.x, a0);
            a1 = fmaf(a, wv.y, a1);
            a2 = fmaf(a, wv.z, a2);
            a3 = fmaf(a, wv.w, a3);
        }
    }

    const int rowi = row0 + rl;
    if (rowi < nrows) {
        unsigned short* hp = &H[(size_t)rowi * 32 + cg * 4];
        hp[0] = f2bf(a0); hp[1] = f2bf(a1); hp[2] = f2bf(a2); hp[3] = f2bf(a3);
    }
}

__global__ void k_gemm_heads(const unsigned short* __restrict__ act,
                             const float* __restrict__ Wmu, const float* __restrict__ Wls,
                             unsigned short* __restrict__ H, int nrows) {
    int idx = blockIdx.x * blockDim.x + threadIdx.x;
    if (idx >= nrows * 32) return;
    int r = idx >> 5;
    int c = idx & 31;
    const float* Wp = (c < 16) ? Wmu : Wls;
    int cc = c & 15;
    float acc = 0.f;
    #pragma unroll 8
    for (int k = 0; k < 32; k++)
        acc = fmaf(bf2f(act[(size_t)r * 32 + k]), Wp[k * 16 + cc], acc);
    H[idx] = f2bf(acc);
}

// ---- aggregation over bf16 H, 8x-unrolled padded CSR; bf16 out ----

template <int F, bool RELU, bool HASBIAS, bool USEW>
__global__ __launch_bounds__(256) void k_aggb(const unsigned short* __restrict__ Hb,
                                              unsigned short* __restrict__ out,
                                              const int* __restrict__ offs,
                                              const unsigned long long* __restrict__ edges,
                                              const int* __restrict__ src,
                                              const float* __restrict__ dinv,
                                              const float* __restrict__ bias,
                                              int nnodes, int Ecap) {
    constexpr int TPN = (F >= 128) ? 64 : F / 2;
    int t = blockIdx.x * 256 + threadIdx.x;
    int node = t / TPN;
    int ln = t % TPN;
    if (node >= nnodes) return;
    int f0 = 2 * ln;

    float di = dinv[node];
    ushort2 sv = *(const ushort2*)&Hb[(size_t)node * F + f0];
    float acc0 = di * bf2f(sv.x);
    float acc1 = di * bf2f(sv.y);

    int s0 = offs[node];
    int s1 = offs[node + 1];
    s0 = imax(0, imin(s0, Ecap));
    s1 = imax(s0, imin(s1, Ecap));
    for (int e = s0; e < s1; e += 8) {
        int sr[8];
        float wv[8];
        if (USEW) {
            #pragma unroll
            for (int q = 0; q < 4; q++) {
                uint4 pr = *(const uint4*)(edges + e + 2 * q);
                sr[2 * q] = (int)pr.x;     wv[2 * q] = __uint_as_float(pr.y);
                sr[2 * q + 1] = (int)pr.z; wv[2 * q + 1] = __uint_as_float(pr.w);
            }
        } else {
            int4 a = *(const int4*)(src + e);
            int4 b = *(const int4*)(src + e + 4);
            sr[0] = a.x; sr[1] = a.y; sr[2] = a.z; sr[3] = a.w;
            sr[4] = b.x; sr[5] = b.y; sr[6] = b.z; sr[7] = b.w;
            #pragma unroll
            for (int q = 0; q < 8; q++) wv[q] = dinv[sr[q]];
        }
        ushort2 h[8];
        #pragma unroll
        for (int q = 0; q < 8; q++)
            h[q] = *(const ushort2*)&Hb[(size_t)sr[q] * F + f0];
        #pragma unroll
        for (int q = 0; q < 8; q++) {
            acc0 = fmaf(wv[q], bf2f(h[q].x), acc0);
            acc1 = fmaf(wv[q], bf2f(h[q].y), acc1);
        }
    }
    float v0 = di * acc0;
    float v1 = di * acc1;
    if (HASBIAS) { v0 += bias[f0]; v1 += bias[f0 + 1]; }
    if (RELU) { v0 = fmaxf(v0, 0.f); v1 = fmaxf(v1, 0.f); }
    ushort2 o; o.x = f2bf(v0); o.y = f2bf(v1);
    *(ushort2*)&out[(size_t)node * F + f0] = o;
}

// fused heads aggregation: F=32 (mu 0..15, logstd 16..31), fp32 split output to d_out
template <bool USEW>
__global__ __launch_bounds__(256) void k_agg_heads(const unsigned short* __restrict__ Hb,
                                                   float* __restrict__ out,
                                                   const int* __restrict__ offs,
                                                   const unsigned long long* __restrict__ edges,
                                                   const int* __restrict__ src,
                                                   const float* __restrict__ dinv,
                                                   const float* __restrict__ bmu, const float* __restrict__ bls,
                                                   int nnodes, int Ecap) {
    constexpr int F = 32, TPN = 16;
    int t = blockIdx.x * 256 + threadIdx.x;
    int node = t / TPN;
    int ln = t % TPN;
    if (node >= nnodes) return;
    int f0 = 2 * ln;

    float di = dinv[node];
    ushort2 sv = *(const ushort2*)&Hb[(size_t)node * F + f0];
    float acc0 = di * bf2f(sv.x);
    float acc1 = di * bf2f(sv.y);

    int s0 = offs[node];
    int s1 = offs[node + 1];
    s0 = imax(0, imin(s0, Ecap));
    s1 = imax(s0, imin(s1, Ecap));
    for (int e = s0; e < s1; e += 8) {
        int sr[8];
        float wv[8];
        if (USEW) {
            #pragma unroll
            for (int q = 0; q < 4; q++) {
                uint4 pr = *(const uint4*)(edges + e + 2 * q);
                sr[2 * q] = (int)pr.x;     wv[2 * q] = __uint_as_float(pr.y);
                sr[2 * q + 1] = (int)pr.z; wv[2 * q + 1] = __uint_as_float(pr.w);
            }
        } else {
            int4 a = *(const int4*)(src + e);
            int4 b = *(const int4*)(src + e + 4);
            sr[0] = a.x; sr[1] = a.y; sr[2] = a.z; sr[3] = a.w;
            sr[4] = b.x; sr[5] = b.y; sr[6] = b.z; sr[7] = b.w;
            #pragma unroll
            for (int q = 0; q < 8; q++) wv[q] = dinv[sr[q]];
        }
        ushort2 h[8];
        #pragma unroll
        for (int q = 0; q < 8; q++)
            h[q] = *(const ushort2*)&Hb[(size_t)sr[q] * F + f0];
        #pragma unroll
        for (int q = 0; q < 8; q++) {
            acc0 = fmaf(wv[q], bf2f(h[q].x), acc0);
            acc1 = fmaf(wv[q], bf2f(h[q].y), acc1);
        }
    }
    const float* bp = (f0 < 16) ? bmu : bls;
    int fb = f0 & 15;
    float v0 = fmaf(di, acc0, bp[fb]);
    float v1 = fmaf(di, acc1, bp[fb + 1]);
    float* op = (f0 < 16) ? (out + (size_t)node * 16 + fb)
                          : (out + (size_t)nnodes * 16 + (size_t)node * 16 + fb);
    *(float2*)op = make_float2(v0, v1);
}

// ---------------- pipeline ----------------

template <bool USEW>
static void run_pipeline(void* const* d_in, void* d_out, void* d_ws,
                         int N, int E, hipStream_t stream) {
    const float* x  = (const float*)d_in[0];
    const int* ei   = (const int*)d_in[1];
    const float* W1 = (const float*)d_in[2];
    const float* b1 = (const float*)d_in[3];
    const float* W2 = (const float*)d_in[4];
    const float* b2 = (const float*)d_in[5];
    const float* W3 = (const float*)d_in[6];
    const float* b3 = (const float*)d_in[7];
    const float* W4 = (const float*)d_in[8];
    const float* b4 = (const float*)d_in[9];
    const float* Wmu = (const float*)d_in[10];
    const float* bmu = (const float*)d_in[11];
    const float* Wls = (const float*)d_in[12];
    const float* bls = (const float*)d_in[13];
    const int* row = ei;        // edge_index[0] = source
    const int* col = ei + E;    // edge_index[1] = target
    const int nb = (N + 255) / 256;
    const int E8 = E + 8 * N;   // capacity with pad-to-8

    auto align16 = [](char* p) {
        return (char*)(((uintptr_t)p + 15) & ~(uintptr_t)15);
    };
    char* p = (char*)d_ws;
    unsigned short* act = (unsigned short*)p;    p += (size_t)N * 256 * 2;
    unsigned short* H = (unsigned short*)p;      p += (size_t)N * 256 * 2;
    unsigned short* xb = H;                      // alias (dead before H first write)
    unsigned short* xa = (unsigned short*)p;     p += (size_t)N * 128 * 2;
    float* dinv = (float*)p;                     p += (size_t)N * 4;
    int* cnt = (int*)p;                          p += (size_t)N * 4;
    int* offs = (int*)p;                         p += (size_t)(N + 1) * 4;
    int* partial = (int*)p;                      p += (size_t)N * 4;
    int* bsum = (int*)p;                         p += (size_t)nb * 4;
    int* bsumoff = (int*)p;                      p += (size_t)nb * 4;
    p = align16(p);
    int* rank = (int*)p;                         p += (size_t)E * 4;
    p = align16(p);
    unsigned short* W1T = (unsigned short*)p;    p += 256 * 128 * 2;
    unsigned short* W2T = (unsigned short*)p;    p += 128 * 256 * 2;
    unsigned short* W3T = (unsigned short*)p;    p += 64 * 128 * 2;
    p = align16(p);
    unsigned long long* edges = nullptr;
    int* csr_src = nullptr;
    if (USEW) edges = (unsigned long long*)p;
    else      csr_src = (int*)p;

    // prologue: zero cnt, x->bf16, weight casts (one kernel)
    {
        size_t total = (size_t)N + (size_t)N * 128 + (128 * 256 + 256 * 128 + 128 * 64);
        k_prologue<<<(unsigned)((total + 255) / 256), 256, 0, stream>>>(
            cnt, N, x, xb, (size_t)N * 128, W1, W1T, W2, W2T, W3, W3T);
    }
    // CSR + norms (atomic-free fill via rank; pad fused into scan3)
    k_count<<<(E + 255) / 256, 256, 0, stream>>>(col, cnt, rank, E, N);
    k_scan1<<<nb, 256, 0, stream>>>(cnt, partial, bsum, N);
    k_scan2<<<1, 256, 0, stream>>>(bsum, bsumoff, nb);
    k_scan3<USEW><<<nb, 256, 0, stream>>>(partial, bsumoff, cnt, offs, dinv, edges, csr_src, N);
    k_fill<USEW><<<(E + 255) / 256, 256, 0, stream>>>(row, col, offs, rank, dinv, edges, csr_src, E, N, E8);

    const int gx = (N + 127) / 128;
    // layer 1: act1 = relu( (Â x) W1 + b1 )
    k_aggb<128, false, false, USEW><<<(unsigned)(((size_t)N * 64 + 255) / 256), 256, 0, stream>>>(xb, xa, offs, edges, csr_src, dinv, nullptr, N, E8);
    k_gemm_mfma<128, 256, true><<<dim3(gx, 2), 256, 0, stream>>>(xa, W1T, act, b1, N, 128);
    // layer 2
    k_gemm_mfma<128, 128, false><<<dim3(gx, 1), 256, 0, stream>>>(act, W2T, H, nullptr, N, 256);
    k_aggb<128, true, true, USEW><<<(unsigned)(((size_t)N * 64 + 255) / 256), 256, 0, stream>>>(H, act, offs, edges, csr_src, dinv, b2, N, E8);
    // layer 3
    k_gemm_mfma<64, 64, false><<<dim3(gx, 1), 256, 0, stream>>>(act, W3T, H, nullptr, N, 128);
    k_aggb<64, true, true, USEW><<<(unsigned)(((size_t)N * 32 + 255) / 256), 256, 0, stream>>>(H, act, offs, edges, csr_src, dinv, b3, N, E8);
    // layer 4
    k_gemm32<<<(N + 31) / 32, 256, 0, stream>>>(act, W4, H, N);
    k_aggb<32, true, true, USEW><<<(unsigned)(((size_t)N * 16 + 255) / 256), 256, 0, stream>>>(H, act, offs, edges, csr_src, dinv, b4, N, E8);
    // fused heads
    float* outF = (float*)d_out;
    k_gemm_heads<<<(unsigned)(((size_t)N * 32 + 255) / 256), 256, 0, stream>>>(act, Wmu, Wls, H, N);
    k_agg_heads<USEW><<<(unsigned)(((size_t)N * 16 + 255) / 256), 256, 0, stream>>>(H, outF, offs, edges, csr_src, dinv, bmu, bls, N, E8);
}

extern "C" void kernel_launch(void* const* d_in, const int* in_sizes, int n_in,
                              void* d_out, int out_size, void* d_ws, size_t ws_size,
                              hipStream_t stream) {
    const int N = in_sizes[0] / 128;
    const int E = in_sizes[1] / 2;
    const int nb = (N + 255) / 256;
    const size_t E8 = (size_t)E + 8 * (size_t)N;

    size_t fixed = (size_t)N * 256 * 2 * 2 + (size_t)N * 128 * 2
                 + (size_t)N * 4 * 4 + 4 + (size_t)nb * 8 + (size_t)E * 4
                 + (256 * 128 + 128 * 256 + 64 * 128) * 2 + 128;
    size_t need_w = fixed + E8 * 8;
    if (ws_size >= need_w)
        run_pipeline<true>(d_in, d_out, d_ws, N, E, stream);
    else
        run_pipeline<false>(d_in, d_out, d_ws, N, E, stream);
}

// Round 18
// 340.539 us; speedup vs baseline: 1.1384x; 1.0028x over previous
//
#include <hip/hip_runtime.h>
#include <hip/hip_bf16.h>
#include <stdint.h>

__device__ inline int imin(int a, int b) { return a < b ? a : b; }
__device__ inline int imax(int a, int b) { return a > b ? a : b; }
__device__ inline float bf2f(unsigned short u) {
    return __uint_as_float(((unsigned int)u) << 16);
}
__device__ inline unsigned short f2bf(float v) {
    unsigned int u = __float_as_uint(v);
    unsigned int r = u + 0x7FFFu + ((u >> 16) & 1u);
    return (unsigned short)(r >> 16);
}

typedef __attribute__((ext_vector_type(8))) short short8;   // 8 bf16 = 4 VGPRs
typedef __attribute__((ext_vector_type(4))) float floatx4;  // MFMA C/D

// ---------------- prologue: zero cnt + cast x->bf16 + weight casts ----------------

__global__ void k_prologue(int* __restrict__ cnt, int n,
                           const float* __restrict__ x, unsigned short* __restrict__ xb, size_t nx,
                           const float* __restrict__ W1, unsigned short* __restrict__ W1T,
                           const float* __restrict__ W2, unsigned short* __restrict__ W2T,
                           const float* __restrict__ W3, unsigned short* __restrict__ W3T) {
    size_t i = (size_t)blockIdx.x * 256 + threadIdx.x;
    if (i < (size_t)n) { cnt[i] = 0; }
    size_t j = i - n;
    if (i >= (size_t)n && j < nx) { xb[j] = f2bf(x[j]); }
    size_t k = j - nx;
    const int n1 = 128 * 256, n2 = 256 * 128, n3 = 128 * 64;
    if (j >= nx && k < (size_t)(n1 + n2 + n3)) {
        int idx = (int)k;
        if (idx < n1) {
            int kk = idx >> 8, nn = idx & 255;            // W1: K=128, Nc=256
            W1T[nn * 128 + kk] = f2bf(W1[idx]);
        } else if (idx < n1 + n2) {
            int jj = idx - n1;
            int kk = jj >> 7, nn = jj & 127;              // W2: K=256, Nc=128
            W2T[nn * 256 + kk] = f2bf(W2[jj]);
        } else {
            int jj = idx - n1 - n2;
            int kk = jj >> 6, nn = jj & 63;               // W3: K=128, Nc=64
            W3T[nn * 128 + kk] = f2bf(W3[jj]);
        }
    }
}

// ---------------- CSR build (padded-to-8 segments, atomic-free fill) ----------------

__global__ void k_count(const int* __restrict__ col, int* __restrict__ cnt,
                        int* __restrict__ rank, int E, int n) {
    int e = blockIdx.x * blockDim.x + threadIdx.x;
    if (e < E) {
        int c = imax(0, imin(col[e], n - 1));
        rank[e] = atomicAdd(&cnt[c], 1);
    }
}

__global__ __launch_bounds__(256) void k_scan1(const int* __restrict__ cnt,
                                               int* __restrict__ partial,
                                               int* __restrict__ bsum, int n) {
    __shared__ int tmp[256];
    int i = blockIdx.x * 256 + threadIdx.x;
    int v = (i < n) ? ((cnt[i] + 7) & ~7) : 0;
    tmp[threadIdx.x] = v;
    __syncthreads();
    #pragma unroll
    for (int s = 1; s < 256; s <<= 1) {
        int t = (threadIdx.x >= s) ? tmp[threadIdx.x - s] : 0;
        __syncthreads();
        tmp[threadIdx.x] += t;
        __syncthreads();
    }
    if (i < n) partial[i] = tmp[threadIdx.x] - v;
    if (threadIdx.x == 255) bsum[blockIdx.x] = tmp[255];
}

__global__ __launch_bounds__(256) void k_scan2(const int* __restrict__ bsum,
                                               int* __restrict__ bsumoff, int nb) {
    __shared__ int tmp[256];
    __shared__ int carry;
    if (threadIdx.x == 0) carry = 0;
    __syncthreads();
    for (int base = 0; base < nb; base += 256) {
        int i = base + threadIdx.x;
        int v = (i < nb) ? bsum[i] : 0;
        tmp[threadIdx.x] = v;
        __syncthreads();
        #pragma unroll
        for (int s = 1; s < 256; s <<= 1) {
            int t = (threadIdx.x >= s) ? tmp[threadIdx.x - s] : 0;
            __syncthreads();
            tmp[threadIdx.x] += t;
            __syncthreads();
        }
        if (i < nb) bsumoff[i] = carry + tmp[threadIdx.x] - v;
        __syncthreads();
        if (threadIdx.x == 0) carry += tmp[255];
        __syncthreads();
    }
}

// scan3 writes offs and the pad slots [offs+cnt, offs+pad8(cnt))
template <bool USEW>
__global__ __launch_bounds__(256) void k_scan3(const int* __restrict__ partial,
                                               const int* __restrict__ bsumoff,
                                               const int* __restrict__ cnt,
                                               int* __restrict__ offs,
                                               float* __restrict__ dinv,
                                               unsigned long long* __restrict__ edges,
                                               int* __restrict__ csr_src,
                                               int n) {
    int i = blockIdx.x * 256 + threadIdx.x;
    if (i >= n) return;
    int v = partial[i] + bsumoff[blockIdx.x];
    int c = imax(cnt[i], 0);
    offs[i] = v;
    if (i == n - 1) offs[n] = v + ((c + 7) & ~7);
    float d = (float)c + 1.0f;
    dinv[i] = rsqrtf(d);
    int end = v + ((c + 7) & ~7);
    for (int p = v + c; p < end; p++) {
        if (USEW) edges[p] = 0ull;
        else csr_src[p] = 0;
    }
}

// atomic-free: pos = offs[col] + rank[e]; pure loads + one independent store.
template <bool USEW>
__global__ void k_fill(const int* __restrict__ row, const int* __restrict__ col,
                       const int* __restrict__ offs, const int* __restrict__ rank,
                       const float* __restrict__ dinv,
                       unsigned long long* __restrict__ edges, int* __restrict__ csr_src,
                       int E, int n, int cap) {
    int e = blockIdx.x * blockDim.x + threadIdx.x;
    if (e >= E) return;
    int c = imax(0, imin(col[e], n - 1));
    int r = imax(0, imin(row[e], n - 1));
    int pos = offs[c] + rank[e];
    pos = imax(0, imin(pos, cap - 1));
    if (USEW) {
        unsigned long long rec = (unsigned long long)(unsigned)r
                               | ((unsigned long long)__float_as_uint(dinv[r]) << 32);
        edges[pos] = rec;
    } else {
        csr_src[pos] = r;
    }
}

// ---------------- MFMA GEMM ----------------

template <int NT, int FOUT, bool EPI>
__global__ __launch_bounds__(256) void k_gemm_mfma(const unsigned short* __restrict__ act,
                                                   const unsigned short* __restrict__ WT,
                                                   unsigned short* __restrict__ H,
                                                   const float* __restrict__ bias,
                                                   int nrows, int Fin) {
    constexpr int CT = NT / 16;
    __shared__ __align__(16) unsigned short sA[128 * 40];
    __shared__ __align__(16) unsigned short sB[NT * 40];
    const int tid = threadIdx.x;
    const int w = tid >> 6;
    const int lane = tid & 63;
    const int quad = lane >> 4;
    const int l15 = lane & 15;
    const int row0 = blockIdx.x * 128;
    const int col0 = blockIdx.y * NT;

    floatx4 acc[2][CT] = {};

    const int sr = tid >> 1;
    const int sp = (tid & 1) * 16;

    for (int k0 = 0; k0 < Fin; k0 += 32) {
        __syncthreads();
        {
            int grow = row0 + sr;
            uint4 v0 = make_uint4(0, 0, 0, 0), v1 = make_uint4(0, 0, 0, 0);
            if (grow < nrows) {
                const uint4* ap = (const uint4*)&act[(size_t)grow * Fin + k0 + sp];
                v0 = ap[0]; v1 = ap[1];
            }
            uint4* dst = (uint4*)&sA[sr * 40 + sp];
            dst[0] = v0; dst[1] = v1;
        }
        if (NT == 128 || tid < 128) {
            const uint4* wp = (const uint4*)&WT[(size_t)(col0 + sr) * Fin + k0 + sp];
            uint4* dst = (uint4*)&sB[sr * 40 + sp];
            dst[0] = wp[0]; dst[1] = wp[1];
        }
        __syncthreads();

        short8 bfr[CT];
        #pragma unroll
        for (int ct = 0; ct < CT; ct++)
            bfr[ct] = *(const short8*)&sB[(ct * 16 + l15) * 40 + quad * 8];
        #pragma unroll
        for (int rt = 0; rt < 2; rt++) {
            short8 afr = *(const short8*)&sA[(w * 32 + rt * 16 + l15) * 40 + quad * 8];
            #pragma unroll
            for (int ct = 0; ct < CT; ct++)
                acc[rt][ct] = __builtin_amdgcn_mfma_f32_16x16x32_bf16(afr, bfr[ct], acc[rt][ct], 0, 0, 0);
        }
    }

    #pragma unroll
    for (int rt = 0; rt < 2; rt++) {
        #pragma unroll
        for (int ct = 0; ct < CT; ct++) {
            int gcol = col0 + ct * 16 + l15;
            #pragma unroll
            for (int r = 0; r < 4; r++) {
                int grow = row0 + w * 32 + rt * 16 + quad * 4 + r;
                if (grow < nrows) {
                    float v = acc[rt][ct][r];
                    if (EPI) v = fmaxf(v + bias[gcol], 0.f);
                    H[(size_t)grow * FOUT + gcol] = f2bf(v);
                }
            }
        }
    }
}

// ---------------- small GEMMs ----------------

__global__ __launch_bounds__(256) void k_gemm32(const unsigned short* __restrict__ act,
                                                const float* __restrict__ W,
                                                unsigned short* __restrict__ H,
                                                int nrows) {
    __shared__ __align__(16) float sA[32 * 68];
    __shared__ __align__(16) float sW[16 * 32];
    const int tid = threadIdx.x;
    const int row0 = blockIdx.x * 32;
    const int Fin = 64, strA = 68;

    for (int i = tid; i < 32 * Fin; i += 256) {
        int r = i >> 6;
        int k = i & 63;
        float v = 0.f;
        if (row0 + r < nrows) v = bf2f(act[(size_t)row0 * Fin + i]);
        sA[r * strA + k] = v;
    }

    const int rl = tid >> 3;
    const int cg = tid & 7;
    float a0 = 0.f, a1 = 0.f, a2 = 0.f, a3 = 0.f;

    for (int k0 = 0; k0 < Fin; k0 += 16) {
        __syncthreads();
        const float* wsrc = W + (size_t)k0 * 32;
        for (int i = tid; i < 16 * 32; i += 256) sW[i] = wsrc[i];
        __syncthreads();
        #pragma unroll 4
        for (int kk = 0; kk < 16; kk++) {
            float a = sA[rl * strA + k0 + kk];
            float4 wv = *(const float4*)&sW[kk * 32 + cg * 4];
            a0 = fmaf(a, wv.x, a0);
            a1 = fmaf(a, wv.y, a1);
            a2 = fmaf(a, wv.z, a2);
            a3 = fmaf(a, wv.w, a3);
        }
    }

    const int rowi = row0 + rl;
    if (rowi < nrows) {
        unsigned short* hp = &H[(size_t)rowi * 32 + cg * 4];
        hp[0] = f2bf(a0); hp[1] = f2bf(a1); hp[2] = f2bf(a2); hp[3] = f2bf(a3);
    }
}

__global__ void k_gemm_heads(const unsigned short* __restrict__ act,
                             const float* __restrict__ Wmu, const float* __restrict__ Wls,
                             unsigned short* __restrict__ H, int nrows) {
    int idx = blockIdx.x * blockDim.x + threadIdx.x;
    if (idx >= nrows * 32) return;
    int r = idx >> 5;
    int c = idx & 31;
    const float* Wp = (c < 16) ? Wmu : Wls;
    int cc = c & 15;
    float acc = 0.f;
    #pragma unroll 8
    for (int k = 0; k < 32; k++)
        acc = fmaf(bf2f(act[(size_t)r * 32 + k]), Wp[k * 16 + cc], acc);
    H[idx] = f2bf(acc);
}

// ---- aggregation over bf16 H; 16-deep gather MLP main loop + 8-wide tail ----

template <int F, bool RELU, bool HASBIAS, bool USEW>
__global__ __launch_bounds__(256) void k_aggb(const unsigned short* __restrict__ Hb,
                                              unsigned short* __restrict__ out,
                                              const int* __restrict__ offs,
                                              const unsigned long long* __restrict__ edges,
                                              const int* __restrict__ src,
                                              const float* __restrict__ dinv,
                                              const float* __restrict__ bias,
                                              int nnodes, int Ecap) {
    constexpr int TPN = (F >= 128) ? 64 : F / 2;
    int t = blockIdx.x * 256 + threadIdx.x;
    int node = t / TPN;
    int ln = t % TPN;
    if (node >= nnodes) return;
    int f0 = 2 * ln;

    float di = dinv[node];
    ushort2 sv = *(const ushort2*)&Hb[(size_t)node * F + f0];
    float acc0 = di * bf2f(sv.x);
    float acc1 = di * bf2f(sv.y);

    int s0 = offs[node];
    int s1 = offs[node + 1];
    s0 = imax(0, imin(s0, Ecap));
    s1 = imax(s0, imin(s1, Ecap));
    int e = s0;
    // main: 16 gathers in flight
    for (; e + 16 <= s1; e += 16) {
        int sr[16];
        float wv[16];
        if (USEW) {
            #pragma unroll
            for (int q = 0; q < 8; q++) {
                uint4 pr = *(const uint4*)(edges + e + 2 * q);
                sr[2 * q] = (int)pr.x;     wv[2 * q] = __uint_as_float(pr.y);
                sr[2 * q + 1] = (int)pr.z; wv[2 * q + 1] = __uint_as_float(pr.w);
            }
        } else {
            #pragma unroll
            for (int q = 0; q < 4; q++) {
                int4 a = *(const int4*)(src + e + 4 * q);
                sr[4 * q] = a.x; sr[4 * q + 1] = a.y; sr[4 * q + 2] = a.z; sr[4 * q + 3] = a.w;
            }
            #pragma unroll
            for (int q = 0; q < 16; q++) wv[q] = dinv[sr[q]];
        }
        ushort2 h[16];
        #pragma unroll
        for (int q = 0; q < 16; q++)
            h[q] = *(const ushort2*)&Hb[(size_t)sr[q] * F + f0];
        #pragma unroll
        for (int q = 0; q < 16; q++) {
            acc0 = fmaf(wv[q], bf2f(h[q].x), acc0);
            acc1 = fmaf(wv[q], bf2f(h[q].y), acc1);
        }
    }
    // tail: 8 at a time (segments are multiples of 8)
    for (; e < s1; e += 8) {
        int sr[8];
        float wv[8];
        if (USEW) {
            #pragma unroll
            for (int q = 0; q < 4; q++) {
                uint4 pr = *(const uint4*)(edges + e + 2 * q);
                sr[2 * q] = (int)pr.x;     wv[2 * q] = __uint_as_float(pr.y);
                sr[2 * q + 1] = (int)pr.z; wv[2 * q + 1] = __uint_as_float(pr.w);
            }
        } else {
            int4 a = *(const int4*)(src + e);
            int4 b = *(const int4*)(src + e + 4);
            sr[0] = a.x; sr[1] = a.y; sr[2] = a.z; sr[3] = a.w;
            sr[4] = b.x; sr[5] = b.y; sr[6] = b.z; sr[7] = b.w;
            #pragma unroll
            for (int q = 0; q < 8; q++) wv[q] = dinv[sr[q]];
        }
        ushort2 h[8];
        #pragma unroll
        for (int q = 0; q < 8; q++)
            h[q] = *(const ushort2*)&Hb[(size_t)sr[q] * F + f0];
        #pragma unroll
        for (int q = 0; q < 8; q++) {
            acc0 = fmaf(wv[q], bf2f(h[q].x), acc0);
            acc1 = fmaf(wv[q], bf2f(h[q].y), acc1);
        }
    }
    float v0 = di * acc0;
    float v1 = di * acc1;
    if (HASBIAS) { v0 += bias[f0]; v1 += bias[f0 + 1]; }
    if (RELU) { v0 = fmaxf(v0, 0.f); v1 = fmaxf(v1, 0.f); }
    ushort2 o; o.x = f2bf(v0); o.y = f2bf(v1);
    *(ushort2*)&out[(size_t)node * F + f0] = o;
}

// fused heads aggregation: F=32 (mu 0..15, logstd 16..31), fp32 split output to d_out
template <bool USEW>
__global__ __launch_bounds__(256) void k_agg_heads(const unsigned short* __restrict__ Hb,
                                                   float* __restrict__ out,
                                                   const int* __restrict__ offs,
                                                   const unsigned long long* __restrict__ edges,
                                                   const int* __restrict__ src,
                                                   const float* __restrict__ dinv,
                                                   const float* __restrict__ bmu, const float* __restrict__ bls,
                                                   int nnodes, int Ecap) {
    constexpr int F = 32, TPN = 16;
    int t = blockIdx.x * 256 + threadIdx.x;
    int node = t / TPN;
    int ln = t % TPN;
    if (node >= nnodes) return;
    int f0 = 2 * ln;

    float di = dinv[node];
    ushort2 sv = *(const ushort2*)&Hb[(size_t)node * F + f0];
    float acc0 = di * bf2f(sv.x);
    float acc1 = di * bf2f(sv.y);

    int s0 = offs[node];
    int s1 = offs[node + 1];
    s0 = imax(0, imin(s0, Ecap));
    s1 = imax(s0, imin(s1, Ecap));
    int e = s0;
    for (; e + 16 <= s1; e += 16) {
        int sr[16];
        float wv[16];
        if (USEW) {
            #pragma unroll
            for (int q = 0; q < 8; q++) {
                uint4 pr = *(const uint4*)(edges + e + 2 * q);
                sr[2 * q] = (int)pr.x;     wv[2 * q] = __uint_as_float(pr.y);
                sr[2 * q + 1] = (int)pr.z; wv[2 * q + 1] = __uint_as_float(pr.w);
            }
        } else {
            #pragma unroll
            for (int q = 0; q < 4; q++) {
                int4 a = *(const int4*)(src + e + 4 * q);
                sr[4 * q] = a.x; sr[4 * q + 1] = a.y; sr[4 * q + 2] = a.z; sr[4 * q + 3] = a.w;
            }
            #pragma unroll
            for (int q = 0; q < 16; q++) wv[q] = dinv[sr[q]];
        }
        ushort2 h[16];
        #pragma unroll
        for (int q = 0; q < 16; q++)
            h[q] = *(const ushort2*)&Hb[(size_t)sr[q] * F + f0];
        #pragma unroll
        for (int q = 0; q < 16; q++) {
            acc0 = fmaf(wv[q], bf2f(h[q].x), acc0);
            acc1 = fmaf(wv[q], bf2f(h[q].y), acc1);
        }
    }
    for (; e < s1; e += 8) {
        int sr[8];
        float wv[8];
        if (USEW) {
            #pragma unroll
            for (int q = 0; q < 4; q++) {
                uint4 pr = *(const uint4*)(edges + e + 2 * q);
                sr[2 * q] = (int)pr.x;     wv[2 * q] = __uint_as_float(pr.y);
                sr[2 * q + 1] = (int)pr.z; wv[2 * q + 1] = __uint_as_float(pr.w);
            }
        } else {
            int4 a = *(const int4*)(src + e);
            int4 b = *(const int4*)(src + e + 4);
            sr[0] = a.x; sr[1] = a.y; sr[2] = a.z; sr[3] = a.w;
            sr[4] = b.x; sr[5] = b.y; sr[6] = b.z; sr[7] = b.w;
            #pragma unroll
            for (int q = 0; q < 8; q++) wv[q] = dinv[sr[q]];
        }
        ushort2 h[8];
        #pragma unroll
        for (int q = 0; q < 8; q++)
            h[q] = *(const ushort2*)&Hb[(size_t)sr[q] * F + f0];
        #pragma unroll
        for (int q = 0; q < 8; q++) {
            acc0 = fmaf(wv[q], bf2f(h[q].x), acc0);
            acc1 = fmaf(wv[q], bf2f(h[q].y), acc1);
        }
    }
    const float* bp = (f0 < 16) ? bmu : bls;
    int fb = f0 & 15;
    float v0 = fmaf(di, acc0, bp[fb]);
    float v1 = fmaf(di, acc1, bp[fb + 1]);
    float* op = (f0 < 16) ? (out + (size_t)node * 16 + fb)
                          : (out + (size_t)nnodes * 16 + (size_t)node * 16 + fb);
    *(float2*)op = make_float2(v0, v1);
}

// ---------------- pipeline ----------------

template <bool USEW>
static void run_pipeline(void* const* d_in, void* d_out, void* d_ws,
                         int N, int E, hipStream_t stream) {
    const float* x  = (const float*)d_in[0];
    const int* ei   = (const int*)d_in[1];
    const float* W1 = (const float*)d_in[2];
    const float* b1 = (const float*)d_in[3];
    const float* W2 = (const float*)d_in[4];
    const float* b2 = (const float*)d_in[5];
    const float* W3 = (const float*)d_in[6];
    const float* b3 = (const float*)d_in[7];
    const float* W4 = (const float*)d_in[8];
    const float* b4 = (const float*)d_in[9];
    const float* Wmu = (const float*)d_in[10];
    const float* bmu = (const float*)d_in[11];
    const float* Wls = (const float*)d_in[12];
    const float* bls = (const float*)d_in[13];
    const int* row = ei;        // edge_index[0] = source
    const int* col = ei + E;    // edge_index[1] = target
    const int nb = (N + 255) / 256;
    const int E8 = E + 8 * N;   // capacity with pad-to-8

    auto align16 = [](char* p) {
        return (char*)(((uintptr_t)p + 15) & ~(uintptr_t)15);
    };
    char* p = (char*)d_ws;
    unsigned short* act = (unsigned short*)p;    p += (size_t)N * 256 * 2;
    unsigned short* H = (unsigned short*)p;      p += (size_t)N * 256 * 2;
    unsigned short* xb = H;                      // alias (dead before H first write)
    unsigned short* xa = (unsigned short*)p;     p += (size_t)N * 128 * 2;
    float* dinv = (float*)p;                     p += (size_t)N * 4;
    int* cnt = (int*)p;                          p += (size_t)N * 4;
    int* offs = (int*)p;                         p += (size_t)(N + 1) * 4;
    int* partial = (int*)p;                      p += (size_t)N * 4;
    int* bsum = (int*)p;                         p += (size_t)nb * 4;
    int* bsumoff = (int*)p;                      p += (size_t)nb * 4;
    p = align16(p);
    int* rank = (int*)p;                         p += (size_t)E * 4;
    p = align16(p);
    unsigned short* W1T = (unsigned short*)p;    p += 256 * 128 * 2;
    unsigned short* W2T = (unsigned short*)p;    p += 128 * 256 * 2;
    unsigned short* W3T = (unsigned short*)p;    p += 64 * 128 * 2;
    p = align16(p);
    unsigned long long* edges = nullptr;
    int* csr_src = nullptr;
    if (USEW) edges = (unsigned long long*)p;
    else      csr_src = (int*)p;

    // prologue: zero cnt, x->bf16, weight casts (one kernel)
    {
        size_t total = (size_t)N + (size_t)N * 128 + (128 * 256 + 256 * 128 + 128 * 64);
        k_prologue<<<(unsigned)((total + 255) / 256), 256, 0, stream>>>(
            cnt, N, x, xb, (size_t)N * 128, W1, W1T, W2, W2T, W3, W3T);
    }
    // CSR + norms (atomic-free fill via rank; pad fused into scan3)
    k_count<<<(E + 255) / 256, 256, 0, stream>>>(col, cnt, rank, E, N);
    k_scan1<<<nb, 256, 0, stream>>>(cnt, partial, bsum, N);
    k_scan2<<<1, 256, 0, stream>>>(bsum, bsumoff, nb);
    k_scan3<USEW><<<nb, 256, 0, stream>>>(partial, bsumoff, cnt, offs, dinv, edges, csr_src, N);
    k_fill<USEW><<<(E + 255) / 256, 256, 0, stream>>>(row, col, offs, rank, dinv, edges, csr_src, E, N, E8);

    const int gx = (N + 127) / 128;
    // layer 1: act1 = relu( (Â x) W1 + b1 )
    k_aggb<128, false, false, USEW><<<(unsigned)(((size_t)N * 64 + 255) / 256), 256, 0, stream>>>(xb, xa, offs, edges, csr_src, dinv, nullptr, N, E8);
    k_gemm_mfma<128, 256, true><<<dim3(gx, 2), 256, 0, stream>>>(xa, W1T, act, b1, N, 128);
    // layer 2
    k_gemm_mfma<128, 128, false><<<dim3(gx, 1), 256, 0, stream>>>(act, W2T, H, nullptr, N, 256);
    k_aggb<128, true, true, USEW><<<(unsigned)(((size_t)N * 64 + 255) / 256), 256, 0, stream>>>(H, act, offs, edges, csr_src, dinv, b2, N, E8);
    // layer 3
    k_gemm_mfma<64, 64, false><<<dim3(gx, 1), 256, 0, stream>>>(act, W3T, H, nullptr, N, 128);
    k_aggb<64, true, true, USEW><<<(unsigned)(((size_t)N * 32 + 255) / 256), 256, 0, stream>>>(H, act, offs, edges, csr_src, dinv, b3, N, E8);
    // layer 4
    k_gemm32<<<(N + 31) / 32, 256, 0, stream>>>(act, W4, H, N);
    k_aggb<32, true, true, USEW><<<(unsigned)(((size_t)N * 16 + 255) / 256), 256, 0, stream>>>(H, act, offs, edges, csr_src, dinv, b4, N, E8);
    // fused heads
    float* outF = (float*)d_out;
    k_gemm_heads<<<(unsigned)(((size_t)N * 32 + 255) / 256), 256, 0, stream>>>(act, Wmu, Wls, H, N);
    k_agg_heads<USEW><<<(unsigned)(((size_t)N * 16 + 255) / 256), 256, 0, stream>>>(H, outF, offs, edges, csr_src, dinv, bmu, bls, N, E8);
}

extern "C" void kernel_launch(void* const* d_in, const int* in_sizes, int n_in,
                              void* d_out, int out_size, void* d_ws, size_t ws_size,
                              hipStream_t stream) {
    const int N = in_sizes[0] / 128;
    const int E = in_sizes[1] / 2;
    const int nb = (N + 255) / 256;
    const size_t E8 = (size_t)E + 8 * (size_t)N;

    size_t fixed = (size_t)N * 256 * 2 * 2 + (size_t)N * 128 * 2
                 + (size_t)N * 4 * 4 + 4 + (size_t)nb * 8 + (size_t)E * 4
                 + (256 * 128 + 128 * 256 + 64 * 128) * 2 + 128;
    size_t need_w = fixed + E8 * 8;
    if (ws_size >= need_w)
        run_pipeline<true>(d_in, d_out, d_ws, N, E, stream);
    else
        run_pipeline<false>(d_in, d_out, d_ws, N, E, stream);
}